// Round 1
// baseline (2224.452 us; speedup 1.0000x reference)
//
#include <hip/hip_runtime.h>

#define BATCH 8192
#define MDIM 128
#define NL 10
#define LSTEPS 97
#define RSTEPS 96
#define DIM 196
#define POSL 98
#define TB 32          // batch rows per chain block
#define PAD 4          // LDS row padding (floats)

// ---------------------------------------------------------------------------
// Transpose w_right: out[i][s][a][n] = in[i][s][n][a]  (192 matrices 128x128)
// grid: (16 tiles, 192 matrices), block 256
// ---------------------------------------------------------------------------
__global__ __launch_bounds__(256) void transpose_wr(const float* __restrict__ in,
                                                    float* __restrict__ out) {
    __shared__ float tile[32][33];
    int mat = blockIdx.y;                 // i*2+s
    int t   = blockIdx.x;                 // 0..15
    int n0  = (t >> 2) * 32;              // input row block (n)
    int a0  = (t & 3) * 32;               // input col block (a)
    const float* src = in + (size_t)mat * MDIM * MDIM;
    float* dst       = out + (size_t)mat * MDIM * MDIM;
    int tx = threadIdx.x & 31;
    int ty = threadIdx.x >> 5;            // 0..7
#pragma unroll
    for (int q = 0; q < 4; ++q) {
        int r = ty + q * 8;
        tile[r][tx] = src[(size_t)(n0 + r) * MDIM + a0 + tx];
    }
    __syncthreads();
#pragma unroll
    for (int q = 0; q < 4; ++q) {
        int r = ty + q * 8;
        dst[(size_t)(a0 + r) * MDIM + n0 + tx] = tile[tx][r];
    }
}

// ---------------------------------------------------------------------------
// Chain kernel: blocks [0, 256) do the left chain, [256, 512) the right chain.
// carry tile (TB x 128) lives in LDS across all steps of the chain.
// Each step: carry_new[b,n] = sum_{s,m} xi[b,s]*carry[b,m]*W[s*128+m][n]
// W staged in 32-row chunks. Per-thread tile: 2 rows x 8 cols.
// ---------------------------------------------------------------------------
__global__ __launch_bounds__(256) void chain_kernel(
        const float* __restrict__ x, const float* __restrict__ w0,
        const float* __restrict__ w_left, const float* __restrict__ w_end,
        const float* __restrict__ wrt,
        float* __restrict__ left_out, float* __restrict__ right_out) {
    __shared__ float c[TB][MDIM + PAD];
    __shared__ float wl[32][MDIM + PAD];

    const int nchain = BATCH / TB;               // 256 blocks per chain
    int bid = blockIdx.x;
    bool is_left = bid < nchain;
    int bb = is_left ? bid : bid - nchain;
    int bbase = bb * TB;
    int tid = threadIdx.x;
    int tn = tid & 15;  int n0 = tn * 8;
    int tb = tid >> 4;  int b0 = tb * 2;         // 2 rows/thread

    // --- initial carry: c[r][m] = x0*wstart[0][m] + x1*wstart[1][m]
    const float* wstart = is_left ? w0 : w_end;
    int pos0 = is_left ? 0 : (DIM - 1);
    {
#pragma unroll
        for (int i = 0; i < 2; ++i) {
            const float2 v = *(const float2*)(x + ((size_t)(bbase + b0 + i) * DIM + pos0) * 2);
#pragma unroll
            for (int j = 0; j < 8; ++j)
                c[b0 + i][n0 + j] = v.x * wstart[n0 + j] + v.y * wstart[MDIM + n0 + j];
        }
    }

    int nsteps = is_left ? LSTEPS : RSTEPS;
    float acc[2][8];

#pragma unroll 1
    for (int step = 0; step < nsteps; ++step) {
        int pos = is_left ? (1 + step) : (DIM - 2 - step);
        const float* Wg = is_left ? (w_left + (size_t)step * 2 * MDIM * MDIM)
                                  : (wrt + (size_t)(RSTEPS - 1 - step) * 2 * MDIM * MDIM);
        float xs[2][2];
#pragma unroll
        for (int i = 0; i < 2; ++i) {
            const float2 v = *(const float2*)(x + ((size_t)(bbase + b0 + i) * DIM + pos) * 2);
            xs[i][0] = v.x; xs[i][1] = v.y;
        }
#pragma unroll
        for (int i = 0; i < 2; ++i)
#pragma unroll
            for (int j = 0; j < 8; ++j) acc[i][j] = 0.f;

#pragma unroll 1
        for (int kc = 0; kc < 8; ++kc) {
            __syncthreads();   // previous chunk's wl reads done / initial c writes visible
            // stage 32 rows x 128 cols of W (4096 floats, 4 float4/thread)
            const float4* src = (const float4*)(Wg + (size_t)kc * 32 * MDIM);
#pragma unroll
            for (int q = 0; q < 4; ++q) {
                int id = tid + q * 256;            // float4 id 0..1023
                int row = id >> 5; int col = (id & 31) << 2;
                *(float4*)&wl[row][col] = src[id];
            }
            __syncthreads();
            int s = kc >> 2;
            float xa0 = xs[0][s], xa1 = xs[1][s];
#pragma unroll
            for (int kk = 0; kk < 32; ++kk) {
                int m = (kc & 3) * 32 + kk;
                float wv[8];
                *(float4*)&wv[0] = *(float4*)&wl[kk][n0];
                *(float4*)&wv[4] = *(float4*)&wl[kk][n0 + 4];
                float a0v = c[b0 + 0][m] * xa0;
                float a1v = c[b0 + 1][m] * xa1;
#pragma unroll
                for (int j = 0; j < 8; ++j) acc[0][j] += a0v * wv[j];
#pragma unroll
                for (int j = 0; j < 8; ++j) acc[1][j] += a1v * wv[j];
            }
        }
        __syncthreads();   // all reads of c for this step complete
#pragma unroll
        for (int i = 0; i < 2; ++i)
#pragma unroll
            for (int j = 0; j < 8; ++j)
                c[b0 + i][n0 + j] = acc[i][j];
        // next iteration's first barrier orders these writes before reads
    }
    __syncthreads();
    // write final carry to global (coalesced, 4 float4/thread)
    float* outp = (is_left ? left_out : right_out) + (size_t)bbase * MDIM;
#pragma unroll
    for (int q = 0; q < 4; ++q) {
        int id = tid + q * 256;                    // float4 id 0..1023 (32*128/4)
        int row = id >> 5; int col = (id & 31) << 2;
        *(float4*)&outp[(size_t)row * MDIM + col] = *(float4*)&c[row][col];
    }
}

// ---------------------------------------------------------------------------
// Label contraction:
// out[b,l] = sum_{p,m,n} xl[b,p] * left[b,m] * right[b,n] * w_label[p,m,n,l]
// Treated as z[b, nl] = (xl-scaled left)[b, pm] @ G[pm, nl] (K=256, N=1280),
// fused with the right[b,n]-weighted reduction over n via LDS partials.
// grid: (10 nl-tiles, 128 batch blocks of 64 rows)
// ---------------------------------------------------------------------------
__global__ __launch_bounds__(256) void label_kernel(
        const float* __restrict__ x, const float* __restrict__ w_label,
        const float* __restrict__ left_in, const float* __restrict__ right_in,
        float* __restrict__ out) {
    __shared__ float c[64][MDIM + PAD];
    __shared__ float wl[32][MDIM + PAD];
    __shared__ float pl[64][NL];

    int nt = blockIdx.x;                   // nl cols [nt*128, +128)
    int bb = blockIdx.y; int bbase = bb * 64;
    int tid = threadIdx.x;
    int tn = tid & 15; int n0 = tn * 8;
    int tb = tid >> 4; int b0 = tb * 4;    // 4 rows/thread

    // load left tile (64x128) coalesced
#pragma unroll
    for (int q = 0; q < 8; ++q) {
        int id = tid + q * 256; int row = id >> 5; int col = (id & 31) << 2;
        *(float4*)&c[row][col] = *(const float4*)&left_in[(size_t)(bbase + row) * MDIM + col];
    }
    for (int q = tid; q < 64 * NL; q += 256) pl[q / NL][q % NL] = 0.f;

    float xs[4][2];
#pragma unroll
    for (int i = 0; i < 4; ++i) {
        const float2 v = *(const float2*)(x + ((size_t)(bbase + b0 + i) * DIM + POSL) * 2);
        xs[i][0] = v.x; xs[i][1] = v.y;
    }
    float acc[4][8];
#pragma unroll
    for (int i = 0; i < 4; ++i)
#pragma unroll
        for (int j = 0; j < 8; ++j) acc[i][j] = 0.f;

#pragma unroll 1
    for (int kc = 0; kc < 8; ++kc) {
        __syncthreads();
        // stage G rows kc*32..+31, cols nt*128..+127 (row stride 1280)
#pragma unroll
        for (int q = 0; q < 4; ++q) {
            int id = tid + q * 256; int row = id >> 5; int col = (id & 31) << 2;
            *(float4*)&wl[row][col] =
                *(const float4*)&w_label[(size_t)(kc * 32 + row) * (MDIM * NL) + (size_t)nt * MDIM + col];
        }
        __syncthreads();
        int s = kc >> 2;   // p index
#pragma unroll
        for (int kk = 0; kk < 32; ++kk) {
            int m = (kc & 3) * 32 + kk;
            float wv[8];
            *(float4*)&wv[0] = *(float4*)&wl[kk][n0];
            *(float4*)&wv[4] = *(float4*)&wl[kk][n0 + 4];
#pragma unroll
            for (int i = 0; i < 4; ++i) {
                float a = c[b0 + i][m] * xs[i][s];
#pragma unroll
                for (int j = 0; j < 8; ++j) acc[i][j] += a * wv[j];
            }
        }
    }
    __syncthreads();
    // fused reduction over n with right[], into LDS per-(row,l) partials
#pragma unroll
    for (int i = 0; i < 4; ++i) {
        int b = bbase + b0 + i;
#pragma unroll
        for (int j = 0; j < 8; ++j) {
            int flat = nt * MDIM + n0 + j;
            int n = flat / NL, l = flat - n * NL;
            float v = acc[i][j] * right_in[(size_t)b * MDIM + n];
            atomicAdd(&pl[b0 + i][l], v);
        }
    }
    __syncthreads();
    for (int q = tid; q < 64 * NL; q += 256) {
        int r = q / NL, l = q - r * NL;
        atomicAdd(&out[(size_t)(bbase + r) * NL + l], pl[r][l]);
    }
}

// ---------------------------------------------------------------------------
extern "C" void kernel_launch(void* const* d_in, const int* in_sizes, int n_in,
                              void* d_out, int out_size, void* d_ws, size_t ws_size,
                              hipStream_t stream) {
    const float* x       = (const float*)d_in[0];
    const float* w0      = (const float*)d_in[1];
    const float* w_left  = (const float*)d_in[2];
    const float* w_label = (const float*)d_in[3];
    const float* w_right = (const float*)d_in[4];
    const float* w_end   = (const float*)d_in[5];

    float* ws      = (float*)d_ws;
    float* wrt     = ws;                                        // 96*2*128*128
    float* left_f  = ws + (size_t)RSTEPS * 2 * MDIM * MDIM;     // 8192*128
    float* right_f = left_f + (size_t)BATCH * MDIM;             // 8192*128

    hipMemsetAsync(d_out, 0, (size_t)out_size * sizeof(float), stream);
    transpose_wr<<<dim3(16, RSTEPS * 2), 256, 0, stream>>>(w_right, wrt);
    chain_kernel<<<dim3(2 * (BATCH / TB)), 256, 0, stream>>>(x, w0, w_left, w_end, wrt,
                                                             left_f, right_f);
    label_kernel<<<dim3(NL, BATCH / 64), 256, 0, stream>>>(x, w_label, left_f, right_f,
                                                           (float*)d_out);
}

// Round 2
// 402.276 us; speedup vs baseline: 5.5297x; 5.5297x over previous
//
#include <hip/hip_runtime.h>

#define BATCH 8192
#define MDIM 128
#define NL 10
#define LSTEPS 97
#define RSTEPS 96
#define NSTEPS 193   // LSTEPS + RSTEPS
#define DIM 196
#define POSL 98

typedef _Float16 half8 __attribute__((ext_vector_type(8)));
typedef float float16v __attribute__((ext_vector_type(16)));

// ---------------------------------------------------------------------------
// Pack weights into f16 A-operand fragment order for v_mfma_f32_32x32x16_f16.
// A-frag (step g, n-tile nt, k-tile kt): lane l, elem j holds
//   W_g[k = kt*16 + (l>>5)*8 + j][n = nt*32 + (l&31)]
// left  (g<97):  W_g[k=s*128+m][n] = w_left[g][s][m][n]
// right (g>=97): t=g-97, W_g[k=s*128+a][n] = w_right[95-t][s][n][a]
// Output: pw[((g*64 + nt*16 + kt)*512) + l*8 + j]  (16B/lane, coalesced)
// ---------------------------------------------------------------------------
__global__ __launch_bounds__(256) void pack_w(const float* __restrict__ w_left,
                                              const float* __restrict__ w_right,
                                              _Float16* __restrict__ pw) {
    int g = blockIdx.x >> 2;
    int nt = blockIdx.x & 3;
    int tid = threadIdx.x;
    int l = tid & 63;
    int kq = tid >> 6;                 // 0..3
    int hi = l >> 5;
    int n = nt * 32 + (l & 31);
#pragma unroll
    for (int p = 0; p < 4; ++p) {
        int kt = p * 4 + kq;
        int k0 = kt * 16 + hi * 8;     // multiple of 8, no s-crossing within 8
        half8 hv;
        if (g < LSTEPS) {
            const float* base = w_left + (size_t)g * 2 * MDIM * MDIM;
#pragma unroll
            for (int j = 0; j < 8; ++j)
                hv[j] = (_Float16)base[(size_t)(k0 + j) * MDIM + n];
        } else {
            int t = g - LSTEPS;
            int s = k0 >> 7;
            int a0 = k0 & 127;
            const float* row = w_right + (size_t)(RSTEPS - 1 - t) * 2 * MDIM * MDIM
                             + (size_t)s * MDIM * MDIM + (size_t)n * MDIM + a0;
#pragma unroll
            for (int j = 0; j < 8; ++j) hv[j] = (_Float16)row[j];
        }
        *(half8*)(pw + (size_t)(g * 64 + nt * 16 + kt) * 512 + l * 8) = hv;
    }
}

// ---------------------------------------------------------------------------
// Chain kernel (f16 MFMA). 512 blocks: [0,256) left chain, [256,512) right.
// TB=32 batch rows/block; 4 waves, wave nt owns output n-range [nt*32, +32).
// D[n][b] = sum_k Wfrag[n][k] * c[b][k%128], two fp32 accumulators per s-half,
// combined as x0*acc0 + x1*acc1 in fp32 (x never rounded to f16).
// Carry c[b][n] f16 in LDS, double-buffered, 16B-block XOR swizzle:
//   phys_block = (n/8) ^ (b & 15); addr = b*256B + phys_block*16B
// ---------------------------------------------------------------------------
__global__ __launch_bounds__(256, 2) void chain_mfma(
        const float* __restrict__ x, const float* __restrict__ w0,
        const float* __restrict__ w_end, const _Float16* __restrict__ pw,
        float* __restrict__ leftT, float* __restrict__ rightT) {
    __shared__ _Float16 cbuf[2][32 * 128];   // 2 x 8 KB

    int bid = blockIdx.x;
    bool is_left = bid < (BATCH / 32);
    int bbase = (is_left ? bid : bid - BATCH / 32) * 32;
    int tid = threadIdx.x;
    int l = tid & 63;
    int nt = tid >> 6;       // wave id = n-tile
    int bl = l & 31;         // batch col (MFMA D col)
    int hi = l >> 5;

    // --- initial carry: c0[b][n] = x0*wstart[0][n] + x1*wstart[1][n]
    {
        const float* wst = is_left ? w0 : w_end;
        int pos0 = is_left ? 0 : (DIM - 1);
        int b = tid >> 3;
        const float2 xv = *(const float2*)(x + ((size_t)(bbase + b) * DIM + pos0) * 2);
#pragma unroll
        for (int h = 0; h < 2; ++h) {
            int nb = (tid & 7) * 2 + h;
            half8 hv;
#pragma unroll
            for (int j = 0; j < 8; ++j) {
                int n = nb * 8 + j;
                hv[j] = (_Float16)(xv.x * wst[n] + xv.y * wst[MDIM + n]);
            }
            int phys = nb ^ (b & 15);
            *(half8*)&cbuf[0][b * 128 + phys * 8] = hv;
        }
    }
    __syncthreads();

    int nsteps = is_left ? LSTEPS : RSTEPS;
    int gbase = is_left ? 0 : LSTEPS;
    float* outT = is_left ? leftT : rightT;

#pragma unroll 1
    for (int step = 0; step < nsteps; ++step) {
        int pos = is_left ? (1 + step) : (DIM - 2 - step);
        const _Float16* cc = cbuf[step & 1];
        _Float16* cn = cbuf[(step & 1) ^ 1];

        const float2 xv = *(const float2*)(x + ((size_t)(bbase + bl) * DIM + pos) * 2);

        // B-frags: lane holds c[bl][ (kt%8)*16 + hi*8 + j ] — 8 unique, reused for s=1
        half8 bf[8];
#pragma unroll
        for (int q = 0; q < 8; ++q) {
            int nb = q * 2 + hi;
            int phys = nb ^ (bl & 15);
            bf[q] = *(const half8*)&cc[bl * 128 + phys * 8];
        }

        const half8* pA = (const half8*)(pw + (size_t)((gbase + step) * 64 + nt * 16) * 512);
        float16v acc0 = {};
        float16v acc1 = {};
#pragma unroll
        for (int kt = 0; kt < 8; ++kt) {
            half8 a = pA[(size_t)kt * 64 + l];
            acc0 = __builtin_amdgcn_mfma_f32_32x32x16_f16(a, bf[kt], acc0, 0, 0, 0);
        }
#pragma unroll
        for (int kt = 8; kt < 16; ++kt) {
            half8 a = pA[(size_t)kt * 64 + l];
            acc1 = __builtin_amdgcn_mfma_f32_32x32x16_f16(a, bf[kt - 8], acc1, 0, 0, 0);
        }

        if (step + 1 < nsteps) {
            // epilogue: c_new = x0*acc0 + x1*acc1 (fp32), cvt f16, swizzled b64 writes
#pragma unroll
            for (int rq = 0; rq < 4; ++rq) {
                int nb = nt * 4 + rq;
                int phys = nb ^ (bl & 15);
                _Float16* dst = &cn[bl * 128 + phys * 8 + hi * 4];
                // rows: n = nt*32 + rq*8 + hi*4 + r, r=0..3 (reg = rq*4+r)
                union { half8 v8; struct { _Float16 a[8]; } s; } u;  // use low 4
#pragma unroll
                for (int r = 0; r < 4; ++r)
                    u.s.a[r] = (_Float16)(xv.x * acc0[rq * 4 + r] + xv.y * acc1[rq * 4 + r]);
                *(uint2*)dst = *(uint2*)&u.s.a[0];   // 8B store
            }
            __syncthreads();
        } else {
            // final step: store fp32 transposed [n][BATCH] (coalesced per half-wave)
#pragma unroll
            for (int r = 0; r < 16; ++r) {
                int n = nt * 32 + (r & 3) + 8 * (r >> 2) + 4 * hi;
                outT[(size_t)n * BATCH + bbase + bl] = xv.x * acc0[r] + xv.y * acc1[r];
            }
        }
    }
}

// ---------------------------------------------------------------------------
// Label contraction (fp32, as round 1) adapted to transposed left/right
// inputs: leftT/rightT are [128][BATCH].
// out[b,l] = sum_{p,m,n} xl[b,p]*left[b,m]*right[b,n]*w_label[p,m,n,l]
// ---------------------------------------------------------------------------
__global__ __launch_bounds__(256) void label_kernel(
        const float* __restrict__ x, const float* __restrict__ w_label,
        const float* __restrict__ leftT, const float* __restrict__ rightT,
        float* __restrict__ out) {
    __shared__ float c[64][MDIM + 4];
    __shared__ float wl[32][MDIM + 4];
    __shared__ float pl[64][NL];

    int nt = blockIdx.x;                   // nl cols [nt*128, +128)
    int bb = blockIdx.y; int bbase = bb * 64;
    int tid = threadIdx.x;
    int tn = tid & 15; int n0 = tn * 8;
    int tb = tid >> 4; int b0 = tb * 4;    // 4 rows/thread

    // load left tile (64 rows x 128 m) from transposed source
#pragma unroll
    for (int q = 0; q < 8; ++q) {
        int fid = tid + q * 256;           // 0..2047
        int m = fid >> 4; int bq = fid & 15;
        float4 v = *(const float4*)&leftT[(size_t)m * BATCH + bbase + bq * 4];
        c[bq * 4 + 0][m] = v.x; c[bq * 4 + 1][m] = v.y;
        c[bq * 4 + 2][m] = v.z; c[bq * 4 + 3][m] = v.w;
    }
    for (int q = tid; q < 64 * NL; q += 256) pl[q / NL][q % NL] = 0.f;

    float xs[4][2];
#pragma unroll
    for (int i = 0; i < 4; ++i) {
        const float2 v = *(const float2*)(x + ((size_t)(bbase + b0 + i) * DIM + POSL) * 2);
        xs[i][0] = v.x; xs[i][1] = v.y;
    }
    float acc[4][8];
#pragma unroll
    for (int i = 0; i < 4; ++i)
#pragma unroll
        for (int j = 0; j < 8; ++j) acc[i][j] = 0.f;

#pragma unroll 1
    for (int kc = 0; kc < 8; ++kc) {
        __syncthreads();
#pragma unroll
        for (int q = 0; q < 4; ++q) {
            int id = tid + q * 256; int row = id >> 5; int col = (id & 31) << 2;
            *(float4*)&wl[row][col] =
                *(const float4*)&w_label[(size_t)(kc * 32 + row) * (MDIM * NL) + (size_t)nt * MDIM + col];
        }
        __syncthreads();
        int s = kc >> 2;   // p index
#pragma unroll
        for (int kk = 0; kk < 32; ++kk) {
            int m = (kc & 3) * 32 + kk;
            float wv[8];
            *(float4*)&wv[0] = *(float4*)&wl[kk][n0];
            *(float4*)&wv[4] = *(float4*)&wl[kk][n0 + 4];
#pragma unroll
            for (int i = 0; i < 4; ++i) {
                float a = c[b0 + i][m] * xs[i][s];
#pragma unroll
                for (int j = 0; j < 8; ++j) acc[i][j] += a * wv[j];
            }
        }
    }
    __syncthreads();
    // overwrite c with the right tile (left no longer needed)
#pragma unroll
    for (int q = 0; q < 8; ++q) {
        int fid = tid + q * 256;
        int n = fid >> 4; int bq = fid & 15;
        float4 v = *(const float4*)&rightT[(size_t)n * BATCH + bbase + bq * 4];
        c[bq * 4 + 0][n] = v.x; c[bq * 4 + 1][n] = v.y;
        c[bq * 4 + 2][n] = v.z; c[bq * 4 + 3][n] = v.w;
    }
    __syncthreads();
    // fused reduction over n with right[], into LDS per-(row,l) partials
#pragma unroll
    for (int i = 0; i < 4; ++i) {
#pragma unroll
        for (int j = 0; j < 8; ++j) {
            int flat = nt * MDIM + n0 + j;
            int n = flat / NL, lb = flat - n * NL;
            float v = acc[i][j] * c[b0 + i][n];
            atomicAdd(&pl[b0 + i][lb], v);
        }
    }
    __syncthreads();
    for (int q = tid; q < 64 * NL; q += 256) {
        int r = q / NL, lb = q - r * NL;
        atomicAdd(&out[(size_t)(bbase + r) * NL + lb], pl[r][lb]);
    }
}

// ---------------------------------------------------------------------------
extern "C" void kernel_launch(void* const* d_in, const int* in_sizes, int n_in,
                              void* d_out, int out_size, void* d_ws, size_t ws_size,
                              hipStream_t stream) {
    const float* x       = (const float*)d_in[0];
    const float* w0      = (const float*)d_in[1];
    const float* w_left  = (const float*)d_in[2];
    const float* w_label = (const float*)d_in[3];
    const float* w_right = (const float*)d_in[4];
    const float* w_end   = (const float*)d_in[5];

    _Float16* pw = (_Float16*)d_ws;                              // 193*64KB = 12.65 MB
    float* leftT  = (float*)((char*)d_ws + (size_t)NSTEPS * 64 * 1024);
    float* rightT = leftT + (size_t)MDIM * BATCH;                // each 4 MB

    hipMemsetAsync(d_out, 0, (size_t)out_size * sizeof(float), stream);
    pack_w<<<dim3(NSTEPS * 4), 256, 0, stream>>>(w_left, w_right, pw);
    chain_mfma<<<dim3(2 * (BATCH / 32)), 256, 0, stream>>>(x, w0, w_end, pw, leftT, rightT);
    label_kernel<<<dim3(NL, BATCH / 64), 256, 0, stream>>>(x, w_label, leftT, rightT,
                                                           (float*)d_out);
}

// Round 3
// 256.317 us; speedup vs baseline: 8.6785x; 1.5694x over previous
//
#include <hip/hip_runtime.h>

#define BATCH 8192
#define MDIM 128
#define NL 10
#define LSTEPS 97
#define RSTEPS 96
#define NSTEPS 193   // LSTEPS + RSTEPS
#define DIM 196
#define POSL 98

typedef _Float16 half8 __attribute__((ext_vector_type(8)));
typedef float float16v __attribute__((ext_vector_type(16)));

// lgkm-only barrier: orders LDS ops but lets global prefetch loads (vmcnt)
// stay in flight across the barrier (what __syncthreads forbids).
#define BARRIER_LGKM() asm volatile("s_waitcnt lgkmcnt(0)\ns_barrier" ::: "memory")

// ---------------------------------------------------------------------------
// Pack chain weights into f16 A-fragment order for v_mfma_f32_32x32x16_f16.
// A-frag (step g, n-tile nt, kt): lane l, elem j = W_g[kt*16+(l>>5)*8+j][nt*32+(l&31)]
// left (g<97): W_g[k=s*128+m][n] = w_left[g][s][m][n]
// right(g>=97): t=g-97, W_g[k=s*128+a][n] = w_right[95-t][s][n][a]
// ---------------------------------------------------------------------------
__global__ __launch_bounds__(256) void pack_w(const float* __restrict__ w_left,
                                              const float* __restrict__ w_right,
                                              _Float16* __restrict__ pw) {
    int g = blockIdx.x >> 2;
    int nt = blockIdx.x & 3;
    int tid = threadIdx.x;
    int l = tid & 63;
    int kq = tid >> 6;
    int hi = l >> 5;
    int n = nt * 32 + (l & 31);
#pragma unroll
    for (int p = 0; p < 4; ++p) {
        int kt = p * 4 + kq;
        int k0 = kt * 16 + hi * 8;
        half8 hv;
        if (g < LSTEPS) {
            const float* base = w_left + (size_t)g * 2 * MDIM * MDIM;
#pragma unroll
            for (int j = 0; j < 8; ++j)
                hv[j] = (_Float16)base[(size_t)(k0 + j) * MDIM + n];
        } else {
            int t = g - LSTEPS;
            int s = k0 >> 7;
            int a0 = k0 & 127;
            const float* row = w_right + (size_t)(RSTEPS - 1 - t) * 2 * MDIM * MDIM
                             + (size_t)s * MDIM * MDIM + (size_t)n * MDIM + a0;
#pragma unroll
            for (int j = 0; j < 8; ++j) hv[j] = (_Float16)row[j];
        }
        *(half8*)(pw + (size_t)(g * 64 + nt * 16 + kt) * 512 + l * 8) = hv;
    }
}

// ---------------------------------------------------------------------------
// Pack w_label into f16 A-frag order with l-major columns: G[k=p*128+m][lab*128+n]
// = w_label[p][m][n][lab]. 40 col-tiles (ct) x 16 kt.
// ---------------------------------------------------------------------------
__global__ __launch_bounds__(256) void pack_label(const float* __restrict__ w_label,
                                                  _Float16* __restrict__ gp) {
    int ct = blockIdx.x;               // 0..39
    int tid = threadIdx.x;
    int l = tid & 63;
    int kq = tid >> 6;
    int hi = l >> 5;
    int outcol = ct * 32 + (l & 31);
    int n = outcol & 127;
    int lab = outcol >> 7;
#pragma unroll
    for (int p2 = 0; p2 < 4; ++p2) {
        int kt = p2 * 4 + kq;
        int k0 = kt * 16 + hi * 8;
        int p = k0 >> 7;
        int m0 = k0 & 127;
        half8 hv;
#pragma unroll
        for (int j = 0; j < 8; ++j)
            hv[j] = (_Float16)w_label[(((size_t)p * MDIM + m0 + j) * MDIM + n) * NL + lab];
        *(half8*)(gp + (size_t)(ct * 16 + kt) * 512 + l * 8) = hv;
    }
}

// ---------------------------------------------------------------------------
// Chain kernel v3: 256 blocks x 512 threads. blocks [0,128) left, [128,256) right.
// TB=64 batch rows/block; 8 waves = 4 n-tiles x 2 b-halves. Twin waves (same nt,
// different b-half) read identical A-frags -> L1 reuse, halved L2 traffic.
// A-frags for step+1 prefetched after the MFMAs; lgkm-only barrier keeps them
// in flight across the step boundary.
// ---------------------------------------------------------------------------
__global__ __launch_bounds__(512, 2) void chain_mfma(
        const float* __restrict__ x, const float* __restrict__ w0,
        const float* __restrict__ w_end, const _Float16* __restrict__ pw,
        float* __restrict__ leftT, float* __restrict__ rightT) {
    __shared__ _Float16 cbuf[2][64 * 128];   // 2 x 16 KB

    int bid = blockIdx.x;
    bool is_left = bid < 128;
    int bbase = (is_left ? bid : bid - 128) * 64;
    int tid = threadIdx.x;
    int l = tid & 63;
    int wv = tid >> 6;        // 0..7
    int nt = wv & 3;          // n-tile (twin waves share nt)
    int bh = wv >> 2;         // b-half
    int bl = l & 31;
    int hi = l >> 5;
    int brow = bh * 32 + bl;  // block-local batch row (B/D column)

    // --- initial carry: c0[b][n] = x0*wstart[0][n] + x1*wstart[1][n]
    {
        const float* wst = is_left ? w0 : w_end;
        int pos0 = is_left ? 0 : (DIM - 1);
        int b = tid >> 3;                        // 0..63
        const float2 xv0 = *(const float2*)(x + ((size_t)(bbase + b) * DIM + pos0) * 2);
#pragma unroll
        for (int h = 0; h < 2; ++h) {
            int nb = (tid & 7) * 2 + h;
            half8 hv;
#pragma unroll
            for (int j = 0; j < 8; ++j) {
                int n = nb * 8 + j;
                hv[j] = (_Float16)(xv0.x * wst[n] + xv0.y * wst[MDIM + n]);
            }
            int phys = nb ^ (b & 15);
            *(half8*)&cbuf[0][b * 128 + phys * 8] = hv;
        }
    }
    __syncthreads();

    int nsteps = is_left ? LSTEPS : RSTEPS;
    int gbase = is_left ? 0 : LSTEPS;
    float* outT = is_left ? leftT : rightT;

    // prologue: A-frags + x for step 0
    const _Float16* pwp = pw + (size_t)(gbase * 64 + nt * 16) * 512 + (size_t)l * 8;
    half8 A[16];
#pragma unroll
    for (int kt = 0; kt < 16; ++kt)
        A[kt] = *(const half8*)(pwp + (size_t)kt * 512);
    float2 xv = *(const float2*)(x + ((size_t)(bbase + brow) * DIM
                                      + (is_left ? 1 : DIM - 2)) * 2);

#pragma unroll 1
    for (int step = 0; step < nsteps; ++step) {
        const _Float16* cc = cbuf[step & 1];
        _Float16* cn = cbuf[(step & 1) ^ 1];

        // B-frags: lane holds c[brow][kt*16 + hi*8 + j]
        half8 bf[8];
#pragma unroll
        for (int q = 0; q < 8; ++q) {
            int nb = q * 2 + hi;
            int phys = nb ^ (brow & 15);
            bf[q] = *(const half8*)&cc[brow * 128 + phys * 8];
        }

        float16v acc0 = {}, acc1 = {};
#pragma unroll
        for (int kt = 0; kt < 8; ++kt) {         // two independent chains interleaved
            acc0 = __builtin_amdgcn_mfma_f32_32x32x16_f16(A[kt], bf[kt], acc0, 0, 0, 0);
            acc1 = __builtin_amdgcn_mfma_f32_32x32x16_f16(A[kt + 8], bf[kt], acc1, 0, 0, 0);
        }

        // prefetch A + x for step+1 (clamped; flies across the barrier)
        const _Float16* pwn = (step + 1 < nsteps) ? (pwp + (size_t)64 * 512) : pwp;
#pragma unroll
        for (int kt = 0; kt < 16; ++kt)
            A[kt] = *(const half8*)(pwn + (size_t)kt * 512);
        pwp = pwn;
        float2 xc = xv;
        {
            int npos = is_left ? (2 + step) : (DIM - 3 - step);   // in [0,195] always
            xv = *(const float2*)(x + ((size_t)(bbase + brow) * DIM + npos) * 2);
        }

        if (step + 1 < nsteps) {
            // epilogue: c_new = x0*acc0 + x1*acc1 (fp32), cvt f16, swizzled 8B writes
#pragma unroll
            for (int rq = 0; rq < 4; ++rq) {
                int nb = nt * 4 + rq;
                int phys = nb ^ (brow & 15);
                union { _Float16 h[4]; uint2 u; } t;
#pragma unroll
                for (int r = 0; r < 4; ++r)
                    t.h[r] = (_Float16)(xc.x * acc0[rq * 4 + r] + xc.y * acc1[rq * 4 + r]);
                *(uint2*)&cn[brow * 128 + phys * 8 + hi * 4] = t.u;
            }
            BARRIER_LGKM();
        } else {
            // final step: store fp32 transposed [n][BATCH] (coalesced)
#pragma unroll
            for (int r = 0; r < 16; ++r) {
                int n = nt * 32 + (r & 3) + 8 * (r >> 2) + 4 * hi;
                outT[(size_t)n * BATCH + bbase + brow] = xc.x * acc0[r] + xc.y * acc1[r];
            }
        }
    }
}

// ---------------------------------------------------------------------------
// Label contraction via MFMA. grid (2 l-halves, 256 batch tiles of 32).
// R[b][k=p*128+m] = xl[b,p]*left[b,m] (f16, LDS, swizzled) is the B operand;
// packed G is the A operand. Column tile ct = l*4 + q has a single label l,
// n-range [q*32,+32) -> right-weighted n-reduce = 16 reg FMAs + shfl_xor(32).
// ---------------------------------------------------------------------------
__global__ __launch_bounds__(256, 2) void label_mfma(
        const float* __restrict__ x, const _Float16* __restrict__ gp,
        const float* __restrict__ leftT, const float* __restrict__ rightT,
        float* __restrict__ out) {
    __shared__ _Float16 R[32 * 256];     // 16 KB
    __shared__ float pl[4][32][5];
    __shared__ float xl_s[32][2];

    int bx = blockIdx.x;                 // 0/1 -> labels [bx*5, +5)
    int bbase = blockIdx.y * 32;
    int tid = threadIdx.x;
    int l = tid & 63, nt = tid >> 6, bl = l & 31, hi = l >> 5;

    if (tid < 32) {
        const float2 v = *(const float2*)(x + ((size_t)(bbase + tid) * DIM + POSL) * 2);
        xl_s[tid][0] = v.x; xl_s[tid][1] = v.y;
    }
    __syncthreads();

    // build R (one-time)
#pragma unroll
    for (int q = 0; q < 4; ++q) {
        int id = tid + q * 256;          // 0..1023
        int m = id >> 3;
        int b4 = (id & 7) * 4;
        float4 v = *(const float4*)&leftT[(size_t)m * BATCH + bbase + b4];
        float vv[4] = {v.x, v.y, v.z, v.w};
#pragma unroll
        for (int bi = 0; bi < 4; ++bi) {
            int b = b4 + bi;
            int kb0 = m >> 3;
            int ph0 = (kb0 & 16) | ((kb0 ^ b) & 15);
            R[b * 256 + ph0 * 8 + (m & 7)] = (_Float16)(xl_s[b][0] * vv[bi]);
            int kb1 = kb0 + 16;
            int ph1 = (kb1 & 16) | ((kb1 ^ b) & 15);
            R[b * 256 + ph1 * 8 + (m & 7)] = (_Float16)(xl_s[b][1] * vv[bi]);
        }
    }

    // right values for this lane's 16 D-rows (n = nt*32 + rowmap(r))
    float rv[16];
#pragma unroll
    for (int r = 0; r < 16; ++r) {
        int n = nt * 32 + (r & 3) + 8 * (r >> 2) + 4 * hi;
        rv[r] = rightT[(size_t)n * BATCH + bbase + bl];
    }
    __syncthreads();

    // R B-frags (shared across all 5 label tiles)
    half8 rf[16];
#pragma unroll
    for (int kt = 0; kt < 16; ++kt) {
        int kb = kt * 2 + hi;
        int ph = (kb & 16) | ((kb ^ bl) & 15);
        rf[kt] = *(const half8*)&R[bl * 256 + ph * 8];
    }

    int l0 = bx * 5;
    float outv[5];
#pragma unroll
    for (int li = 0; li < 5; ++li) {
        int ct = (l0 + li) * 4 + nt;
        float16v acc = {};
#pragma unroll
        for (int kt = 0; kt < 16; ++kt) {
            half8 a = *(const half8*)(gp + (size_t)(ct * 16 + kt) * 512 + l * 8);
            acc = __builtin_amdgcn_mfma_f32_32x32x16_f16(a, rf[kt], acc, 0, 0, 0);
        }
        float p = 0.f;
#pragma unroll
        for (int r = 0; r < 16; ++r) p += acc[r] * rv[r];
        p += __shfl_xor(p, 32, 64);      // combine hi-pair rows
        outv[li] = p;
    }
    if (hi == 0) {
#pragma unroll
        for (int li = 0; li < 5; ++li) pl[nt][bl][li] = outv[li];
    }
    __syncthreads();
    if (tid < 160) {
        int b = tid / 5, li = tid % 5;
        out[(size_t)(bbase + b) * NL + l0 + li] =
            pl[0][b][li] + pl[1][b][li] + pl[2][b][li] + pl[3][b][li];
    }
}

// ---------------------------------------------------------------------------
extern "C" void kernel_launch(void* const* d_in, const int* in_sizes, int n_in,
                              void* d_out, int out_size, void* d_ws, size_t ws_size,
                              hipStream_t stream) {
    const float* x       = (const float*)d_in[0];
    const float* w0      = (const float*)d_in[1];
    const float* w_left  = (const float*)d_in[2];
    const float* w_label = (const float*)d_in[3];
    const float* w_right = (const float*)d_in[4];
    const float* w_end   = (const float*)d_in[5];

    _Float16* pw = (_Float16*)d_ws;                               // 12.64 MB
    _Float16* gp = pw + (size_t)NSTEPS * 64 * 512;                // 0.66 MB
    float* leftT  = (float*)(gp + (size_t)40 * 16 * 512);         // 4 MB
    float* rightT = leftT + (size_t)MDIM * BATCH;                 // 4 MB

    pack_w<<<dim3(NSTEPS * 4), 256, 0, stream>>>(w_left, w_right, pw);
    pack_label<<<dim3(40), 256, 0, stream>>>(w_label, gp);
    chain_mfma<<<dim3(256), 512, 0, stream>>>(x, w0, w_end, pw, leftT, rightT);
    label_mfma<<<dim3(2, BATCH / 32), 256, 0, stream>>>(x, gp, leftT, rightT,
                                                        (float*)d_out);
}

// Round 4
// 249.361 us; speedup vs baseline: 8.9206x; 1.0279x over previous
//
#include <hip/hip_runtime.h>

#define BATCH 8192
#define MDIM 128
#define NL 10
#define LSTEPS 97
#define RSTEPS 96
#define NSTEPS 193   // LSTEPS + RSTEPS
#define DIM 196
#define POSL 98

typedef _Float16 half8 __attribute__((ext_vector_type(8)));
typedef float float16v __attribute__((ext_vector_type(16)));

// lgkm-only barrier: orders LDS ops but lets vm ops (DMA/global loads) fly.
#define BARRIER_LGKM() asm volatile("s_waitcnt lgkmcnt(0)\ns_barrier" ::: "memory")
// full barrier: drains the A-DMA (vmcnt) + LDS writes, then s_barrier.
#define BARRIER_FULL() asm volatile("s_waitcnt vmcnt(0) lgkmcnt(0)\ns_barrier" ::: "memory")

// async 16B/lane global->LDS DMA: lds dest = wave-uniform base + lane*16
__device__ __forceinline__ void dma16(const void* g, void* l) {
    __builtin_amdgcn_global_load_lds(
        (const __attribute__((address_space(1))) void*)g,
        (__attribute__((address_space(3))) void*)l, 16, 0, 0);
}

// ---------------------------------------------------------------------------
// Pack chain weights into f16 A-fragment order for v_mfma_f32_32x32x16_f16.
// A-frag (step g, n-tile nt, kt): lane l, elem j = W_g[kt*16+(l>>5)*8+j][nt*32+(l&31)]
// left (g<97): W_g[k=s*128+m][n] = w_left[g][s][m][n]
// right(g>=97): t=g-97, W_g[k=s*128+a][n] = w_right[95-t][s][n][a]
// ---------------------------------------------------------------------------
__global__ __launch_bounds__(256) void pack_w(const float* __restrict__ w_left,
                                              const float* __restrict__ w_right,
                                              _Float16* __restrict__ pw) {
    int g = blockIdx.x >> 2;
    int nt = blockIdx.x & 3;
    int tid = threadIdx.x;
    int l = tid & 63;
    int kq = tid >> 6;
    int hi = l >> 5;
    int n = nt * 32 + (l & 31);
#pragma unroll
    for (int p = 0; p < 4; ++p) {
        int kt = p * 4 + kq;
        int k0 = kt * 16 + hi * 8;
        half8 hv;
        if (g < LSTEPS) {
            const float* base = w_left + (size_t)g * 2 * MDIM * MDIM;
#pragma unroll
            for (int j = 0; j < 8; ++j)
                hv[j] = (_Float16)base[(size_t)(k0 + j) * MDIM + n];
        } else {
            int t = g - LSTEPS;
            int s = k0 >> 7;
            int a0 = k0 & 127;
            const float* row = w_right + (size_t)(RSTEPS - 1 - t) * 2 * MDIM * MDIM
                             + (size_t)s * MDIM * MDIM + (size_t)n * MDIM + a0;
#pragma unroll
            for (int j = 0; j < 8; ++j) hv[j] = (_Float16)row[j];
        }
        *(half8*)(pw + (size_t)(g * 64 + nt * 16 + kt) * 512 + l * 8) = hv;
    }
}

// ---------------------------------------------------------------------------
// Pack w_label into f16 A-frag order with l-major columns: G[k=p*128+m][lab*128+n]
// ---------------------------------------------------------------------------
__global__ __launch_bounds__(256) void pack_label(const float* __restrict__ w_label,
                                                  _Float16* __restrict__ gp) {
    int ct = blockIdx.x;               // 0..39
    int tid = threadIdx.x;
    int l = tid & 63;
    int kq = tid >> 6;
    int hi = l >> 5;
    int outcol = ct * 32 + (l & 31);
    int n = outcol & 127;
    int lab = outcol >> 7;
#pragma unroll
    for (int p2 = 0; p2 < 4; ++p2) {
        int kt = p2 * 4 + kq;
        int k0 = kt * 16 + hi * 8;
        int p = k0 >> 7;
        int m0 = k0 & 127;
        half8 hv;
#pragma unroll
        for (int j = 0; j < 8; ++j)
            hv[j] = (_Float16)w_label[(((size_t)p * MDIM + m0 + j) * MDIM + n) * NL + lab];
        *(half8*)(gp + (size_t)(ct * 16 + kt) * 512 + l * 8) = hv;
    }
}

// ---------------------------------------------------------------------------
// Chain kernel v4: 256 blocks x 512 threads, 1 block/CU.
// A-operand staged via async global_load_lds DMA into double-buffered LDS
// (64 KB/step, zero VGPR cost — regalloc can't break the prefetch).
// Carry single-buffered in-place: bf reads fully captured in regs, then
// lgkm-only barrier, MFMAs read A from LDS, epilogue writes carry, full
// barrier (vmcnt drain = DMA issued a whole step earlier).
// ---------------------------------------------------------------------------
__global__ __launch_bounds__(512, 2) void chain_mfma(
        const float* __restrict__ x, const float* __restrict__ w0,
        const float* __restrict__ w_end, const _Float16* __restrict__ pw,
        float* __restrict__ leftT, float* __restrict__ rightT) {
    __shared__ _Float16 Abuf[2][64 * 512];   // 2 x 64 KB A staging
    __shared__ _Float16 cbuf[64 * 128];      // 16 KB carry (in-place)

    int bid = blockIdx.x;
    bool is_left = bid < 128;
    int bbase = (is_left ? bid : bid - 128) * 64;
    int tid = threadIdx.x;
    int l = tid & 63;
    int wv = tid >> 6;        // 0..7
    int nt = wv & 3;          // n-tile (b-twins share nt)
    int bh = wv >> 2;         // b-half
    int bl = l & 31;
    int hi = l >> 5;
    int brow = bh * 32 + bl;  // block-local batch row (B/D column)

    int nsteps = is_left ? LSTEPS : RSTEPS;
    int gbase = is_left ? 0 : LSTEPS;
    float* outT = is_left ? leftT : rightT;

    // --- initial carry: c0[b][n] = x0*wstart[0][n] + x1*wstart[1][n]
    {
        const float* wst = is_left ? w0 : w_end;
        int pos0 = is_left ? 0 : (DIM - 1);
        int b = tid >> 3;                        // 0..63
        const float2 xv0 = *(const float2*)(x + ((size_t)(bbase + b) * DIM + pos0) * 2);
#pragma unroll
        for (int h = 0; h < 2; ++h) {
            int nb = (tid & 7) * 2 + h;
            half8 hv;
#pragma unroll
            for (int j = 0; j < 8; ++j) {
                int n = nb * 8 + j;
                hv[j] = (_Float16)(xv0.x * wst[n] + xv0.y * wst[MDIM + n]);
            }
            int phys = nb ^ (b & 15);
            *(half8*)&cbuf[b * 128 + phys * 8] = hv;
        }
    }

    // --- prologue: DMA step-0 A block, load step-0 x
    {
        const char* g0 = (const char*)(pw + (size_t)gbase * 64 * 512);
        char* l0 = (char*)&Abuf[0][0];
        int o = wv * 8192;
#pragma unroll
        for (int r = 0; r < 8; ++r)
            dma16(g0 + o + r * 1024 + l * 16, l0 + o + r * 1024);
    }
    float2 xv = *(const float2*)(x + ((size_t)(bbase + brow) * DIM
                                      + (is_left ? 1 : DIM - 2)) * 2);
    __syncthreads();   // drains DMA (vmcnt) + carry init (lgkm)

#pragma unroll 1
    for (int step = 0; step < nsteps; ++step) {
        const _Float16* Acur = Abuf[step & 1];
        float2 xc = xv;

        // issue DMA for step+1 (flies for the whole step) + prefetch next x
        if (step + 1 < nsteps) {
            const char* gn = (const char*)(pw + (size_t)(gbase + step + 1) * 64 * 512);
            char* ln = (char*)&Abuf[(step + 1) & 1][0];
            int o = wv * 8192;
#pragma unroll
            for (int r = 0; r < 8; ++r)
                dma16(gn + o + r * 1024 + l * 16, ln + o + r * 1024);
            int npos = is_left ? (2 + step) : (DIM - 3 - step);   // always in [0,195]
            xv = *(const float2*)(x + ((size_t)(bbase + brow) * DIM + npos) * 2);
        }

        // B-frags: lane captures full carry row brow into regs
        half8 bf[8];
#pragma unroll
        for (int q = 0; q < 8; ++q) {
            int nb = q * 2 + hi;
            int phys = nb ^ (brow & 15);
            bf[q] = *(const half8*)&cbuf[brow * 128 + phys * 8];
        }
        BARRIER_LGKM();   // carry reads done; DMA still in flight

        float16v acc0 = {}, acc1 = {};
#pragma unroll
        for (int kt = 0; kt < 8; ++kt) {
            half8 a0 = *(const half8*)&Acur[(size_t)(nt * 16 + kt) * 512 + l * 8];
            half8 a1 = *(const half8*)&Acur[(size_t)(nt * 16 + 8 + kt) * 512 + l * 8];
            acc0 = __builtin_amdgcn_mfma_f32_32x32x16_f16(a0, bf[kt], acc0, 0, 0, 0);
            acc1 = __builtin_amdgcn_mfma_f32_32x32x16_f16(a1, bf[kt], acc1, 0, 0, 0);
        }

        if (step + 1 < nsteps) {
            // epilogue: c_new = x0*acc0 + x1*acc1 (fp32), cvt f16, in-place write
#pragma unroll
            for (int rq = 0; rq < 4; ++rq) {
                int nb = nt * 4 + rq;
                int phys = nb ^ (brow & 15);
                union { _Float16 h[4]; uint2 u; } t;
#pragma unroll
                for (int r = 0; r < 4; ++r)
                    t.h[r] = (_Float16)(xc.x * acc0[rq * 4 + r] + xc.y * acc1[rq * 4 + r]);
                *(uint2*)&cbuf[brow * 128 + phys * 8 + hi * 4] = t.u;
            }
            BARRIER_FULL();   // carry writes + A-DMA (issued a full step ago) drained
        } else {
            // final step: store fp32 transposed [n][BATCH] (coalesced)
#pragma unroll
            for (int r = 0; r < 16; ++r) {
                int n = nt * 32 + (r & 3) + 8 * (r >> 2) + 4 * hi;
                outT[(size_t)n * BATCH + bbase + brow] = xc.x * acc0[r] + xc.y * acc1[r];
            }
        }
    }
}

// ---------------------------------------------------------------------------
// Label contraction via MFMA (unchanged from round 3).
// ---------------------------------------------------------------------------
__global__ __launch_bounds__(256, 2) void label_mfma(
        const float* __restrict__ x, const _Float16* __restrict__ gp,
        const float* __restrict__ leftT, const float* __restrict__ rightT,
        float* __restrict__ out) {
    __shared__ _Float16 R[32 * 256];     // 16 KB
    __shared__ float pl[4][32][5];
    __shared__ float xl_s[32][2];

    int bx = blockIdx.x;                 // 0/1 -> labels [bx*5, +5)
    int bbase = blockIdx.y * 32;
    int tid = threadIdx.x;
    int l = tid & 63, nt = tid >> 6, bl = l & 31, hi = l >> 5;

    if (tid < 32) {
        const float2 v = *(const float2*)(x + ((size_t)(bbase + tid) * DIM + POSL) * 2);
        xl_s[tid][0] = v.x; xl_s[tid][1] = v.y;
    }
    __syncthreads();

    // build R (one-time): R[b][k=p*128+m] = xl[b,p]*left[b,m], f16, swizzled
#pragma unroll
    for (int q = 0; q < 4; ++q) {
        int id = tid + q * 256;          // 0..1023
        int m = id >> 3;
        int b4 = (id & 7) * 4;
        float4 v = *(const float4*)&leftT[(size_t)m * BATCH + bbase + b4];
        float vv[4] = {v.x, v.y, v.z, v.w};
#pragma unroll
        for (int bi = 0; bi < 4; ++bi) {
            int b = b4 + bi;
            int kb0 = m >> 3;
            int ph0 = (kb0 & 16) | ((kb0 ^ b) & 15);
            R[b * 256 + ph0 * 8 + (m & 7)] = (_Float16)(xl_s[b][0] * vv[bi]);
            int kb1 = kb0 + 16;
            int ph1 = (kb1 & 16) | ((kb1 ^ b) & 15);
            R[b * 256 + ph1 * 8 + (m & 7)] = (_Float16)(xl_s[b][1] * vv[bi]);
        }
    }

    // right values for this lane's 16 D-rows
    float rv[16];
#pragma unroll
    for (int r = 0; r < 16; ++r) {
        int n = nt * 32 + (r & 3) + 8 * (r >> 2) + 4 * hi;
        rv[r] = rightT[(size_t)n * BATCH + bbase + bl];
    }
    __syncthreads();

    half8 rf[16];
#pragma unroll
    for (int kt = 0; kt < 16; ++kt) {
        int kb = kt * 2 + hi;
        int ph = (kb & 16) | ((kb ^ bl) & 15);
        rf[kt] = *(const half8*)&R[bl * 256 + ph * 8];
    }

    int l0 = bx * 5;
    float outv[5];
#pragma unroll
    for (int li = 0; li < 5; ++li) {
        int ct = (l0 + li) * 4 + nt;
        float16v acc = {};
#pragma unroll
        for (int kt = 0; kt < 16; ++kt) {
            half8 a = *(const half8*)(gp + (size_t)(ct * 16 + kt) * 512 + l * 8);
            acc = __builtin_amdgcn_mfma_f32_32x32x16_f16(a, rf[kt], acc, 0, 0, 0);
        }
        float p = 0.f;
#pragma unroll
        for (int r = 0; r < 16; ++r) p += acc[r] * rv[r];
        p += __shfl_xor(p, 32, 64);
        outv[li] = p;
    }
    if (hi == 0) {
#pragma unroll
        for (int li = 0; li < 5; ++li) pl[nt][bl][li] = outv[li];
    }
    __syncthreads();
    if (tid < 160) {
        int b = tid / 5, li = tid % 5;
        out[(size_t)(bbase + b) * NL + l0 + li] =
            pl[0][b][li] + pl[1][b][li] + pl[2][b][li] + pl[3][b][li];
    }
}

// ---------------------------------------------------------------------------
extern "C" void kernel_launch(void* const* d_in, const int* in_sizes, int n_in,
                              void* d_out, int out_size, void* d_ws, size_t ws_size,
                              hipStream_t stream) {
    const float* x       = (const float*)d_in[0];
    const float* w0      = (const float*)d_in[1];
    const float* w_left  = (const float*)d_in[2];
    const float* w_label = (const float*)d_in[3];
    const float* w_right = (const float*)d_in[4];
    const float* w_end   = (const float*)d_in[5];

    _Float16* pw = (_Float16*)d_ws;                               // 12.64 MB
    _Float16* gp = pw + (size_t)NSTEPS * 64 * 512;                // 0.66 MB
    float* leftT  = (float*)(gp + (size_t)40 * 16 * 512);         // 4 MB
    float* rightT = leftT + (size_t)MDIM * BATCH;                 // 4 MB

    pack_w<<<dim3(NSTEPS * 4), 256, 0, stream>>>(w_left, w_right, pw);
    pack_label<<<dim3(40), 256, 0, stream>>>(w_label, gp);
    chain_mfma<<<dim3(256), 512, 0, stream>>>(x, w0, w_end, pw, leftT, rightT);
    // label_mfma writes every (b,l) exactly once — no memset needed
    label_mfma<<<dim3(2, BATCH / 32), 256, 0, stream>>>(x, gp, leftT, rightT,
                                                        (float*)d_out);
}